// Round 6
// baseline (305.636 us; speedup 1.0000x reference)
//
#include <hip/hip_runtime.h>

#define B_ 16
#define S_ 1024
#define E_ 512
#define H_ 8
#define D_ 64
#define L_ 4
#define M_ (B_*S_)   // 16384 tokens

typedef unsigned short u16;
typedef __attribute__((ext_vector_type(8))) short bf16x8;  // 8 bf16 = 4 VGPRs
typedef __attribute__((ext_vector_type(4))) float f32x4;
typedef __attribute__((ext_vector_type(16))) float f32x16;
typedef __attribute__((ext_vector_type(4))) unsigned uint4v;
typedef __attribute__((ext_vector_type(2))) int int2v;

__device__ __forceinline__ u16 f2bf(float x) {
  unsigned u = __float_as_uint(x);
  unsigned r = (u + 0x7fffu + ((u >> 16) & 1u)) >> 16;  // RNE
  return (u16)r;
}
__device__ __forceinline__ ushort4 f2bf4(float4 f) {
  ushort4 u;
  u.x = f2bf(f.x); u.y = f2bf(f.y); u.z = f2bf(f.z); u.w = f2bf(f.w);
  return u;
}
// single-instruction pack: two f32 -> packed bf16x2 (lo in low half)
__device__ __forceinline__ unsigned cvt_pk_bf16(float lo, float hi) {
  unsigned r;
  asm("v_cvt_pk_bf16_f32 %0, %1, %2" : "=v"(r) : "v"(lo), "v"(hi));
  return r;
}
// permlane32_swap: r[0] = {x.lo, y.lo-moved-to-hi}, r[1] = {x.hi-moved-to-lo, y.hi}
__device__ __forceinline__ int2v plswap(unsigned x, unsigned y) {
  return __builtin_amdgcn_permlane32_swap((int)x, (int)y, false, false);
}

typedef __attribute__((address_space(1))) const void gconst_void;
typedef __attribute__((address_space(3))) void lds_void;
__device__ __forceinline__ void gl_lds16(const void* g, void* l) {
  __builtin_amdgcn_global_load_lds((gconst_void*)g, (lds_void*)l, 16, 0, 0);
}

// ---------------- fused weight prep (all 4 weight matrices + biases) ----------------
__global__ __launch_bounds__(256) void prep_w(
    const float* __restrict__ Wq, const float* __restrict__ Wk,
    const float* __restrict__ Wv_sh, const float* __restrict__ Wv_sp,
    const float* __restrict__ Wo_sh, const float* __restrict__ Wo_sp,
    const float* __restrict__ bv_sh, const float* __restrict__ bv_sp,
    const float* __restrict__ bo_sh, const float* __restrict__ bo_sp,
    const int* __restrict__ langp,
    u16* __restrict__ Wq_b, u16* __restrict__ Wk_b,
    u16* __restrict__ Wv_b, u16* __restrict__ Wo_b,
    float* __restrict__ bv_f, float* __restrict__ bo_f) {
  int lang = langp[0];
  int i = blockIdx.x * 256 + threadIdx.x;           // over E_*E_/4
  size_t wofs = (size_t)lang * (E_*E_/4) + i;
  ((ushort4*)Wq_b)[i] = f2bf4(((const float4*)Wq)[i]);
  ((ushort4*)Wk_b)[i] = f2bf4(((const float4*)Wk)[i]);
  float4 vs = ((const float4*)Wv_sh)[i], vp = ((const float4*)Wv_sp)[wofs];
  float4 os = ((const float4*)Wo_sh)[i], op = ((const float4*)Wo_sp)[wofs];
  float4 vv = {vs.x*vp.x, vs.y*vp.y, vs.z*vp.z, vs.w*vp.w};
  float4 oo = {os.x*op.x, os.y*op.y, os.z*op.z, os.w*op.w};
  ((ushort4*)Wv_b)[i] = f2bf4(vv);
  ((ushort4*)Wo_b)[i] = f2bf4(oo);
  if (i < E_/4) {
    float4 b1 = ((const float4*)bv_sh)[i], b2 = ((const float4*)(bv_sp + (size_t)lang*E_))[i];
    float4 b3 = ((const float4*)bo_sh)[i], b4 = ((const float4*)(bo_sp + (size_t)lang*E_))[i];
    float4 r1 = {b1.x+b2.x, b1.y+b2.y, b1.z+b2.z, b1.w+b2.w};
    float4 r2 = {b3.x+b4.x, b3.y+b4.y, b3.z+b4.z, b3.w+b4.w};
    ((float4*)bv_f)[i] = r1;
    ((float4*)bo_f)[i] = r2;
  }
}

// ---------------- fused QKV projection GEMM: {Q,K,V}b = {q,k,v} @ W^T + b ----------------
// 128x128 tile, BK=32. DEEP PIPELINE (T4 counted vmcnt): B = 4-deep LDS ring via
// gload_lds (inverse-swizzled source), A = 3-deep reg sets (fp32) cvt'd to bf16 and
// ds_written (swizzled) just-in-time into a 2-deep LDS buf. Per-iter batch = 6 VMEM
// ops/wave; steady-state wait = vmcnt(12) (2 batches stay in flight, never drained
// to 0 until tail). One raw barrier per iter. z==2 writes transposed Vt.
__global__ __launch_bounds__(256, 3) void gemm_qkv(
    const float* __restrict__ q, const float* __restrict__ k, const float* __restrict__ v,
    const u16* __restrict__ Wq_b, const u16* __restrict__ Wk_b, const u16* __restrict__ Wv_b,
    const float* __restrict__ bq, const float* __restrict__ bk, const float* __restrict__ bv,
    u16* __restrict__ Qb, u16* __restrict__ Kb, u16* __restrict__ Vt) {
  __shared__ __align__(16) u16 sA[2*4096];   // 16KB: A bf16, 2-deep (publish just-in-time)
  __shared__ __align__(16) u16 sB[4*4096];   // 32KB: B bf16, 4-deep ring
  const int z = blockIdx.y;
  const float* A    = (z == 0) ? q : (z == 1) ? k : v;
  const u16*   Bw   = (z == 0) ? Wq_b : (z == 1) ? Wk_b : Wv_b;
  const float* bias = (z == 0) ? bq : (z == 1) ? bk : bv;
  const int t = threadIdx.x;
  const int hw = blockIdx.x;
  const int wk = (hw & 7) * 64 + (hw >> 3);   // XCD swizzle (bijective)
  const int m0 = (wk >> 2) * 128, n0 = (wk & 3) * 128;
  const int lane = t & 63, wid = t >> 6;
  const int m16 = lane & 15, qq = lane >> 4;
  const int wrow = (wid >> 1) * 64, wcol = (wid & 1) * 64;
  const int key = (lane & 7) << 4;
  f32x4 acc[4][4] = {};
  // A reg-staging: thread t owns row t>>1, 16 floats at col (t&1)*16; 3 rotating sets
  const int arow = t >> 1;
  const float* aR = A + (size_t)(m0 + arow) * E_ + (t & 1) * 16;
  const int awr0 = (arow*64 + (t&1)*32)      ^ ((arow & 7) << 4);
  const int awr1 = (arow*64 + (t&1)*32 + 16) ^ ((arow & 7) << 4);
  f32x4 rA[3][4];
  // B staging: gload_lds, inverse-swizzled source, 2 chunks/wave
  const int cb0 = wid*2, cb1 = wid*2 + 1;
  const int rl0 = ((lane>>2)&1) ^ ((lane>>4)&1);
  const int brow = 2*(lane>>3) + rl0;
  const int bcol = (((lane&1)^rl0)<<3) + ((((lane>>1)&1) ^ ((lane>>3)&1))<<4);
  const u16* bp0 = Bw + (size_t)(n0 + cb0*16 + brow) * E_ + bcol;
  const u16* bp1 = Bw + (size_t)(n0 + cb1*16 + brow) * E_ + bcol;
  char* sAb = (char*)sA;
  char* sBb = (char*)sB;
  // ---- prologue: issue batches 0,1,2 (order per batch: B,B,A,A,A,A) ----
#pragma unroll
  for (int p = 0; p < 3; ++p) {
    gl_lds16(bp0, sBb + p*8192 + cb0*1024);
    gl_lds16(bp1, sBb + p*8192 + cb1*1024);
    rA[p][0] = *(const f32x4*)aR;
    rA[p][1] = *(const f32x4*)(aR + 4);
    rA[p][2] = *(const f32x4*)(aR + 8);
    rA[p][3] = *(const f32x4*)(aR + 12);
    aR += 32; bp0 += 32; bp1 += 32;
  }
#pragma unroll
  for (int kt = 0; kt < 16; ++kt) {
    // drain exactly batch kt (6 ops); keep kt+1, kt+2 in flight
    if (kt < 14)       asm volatile("s_waitcnt vmcnt(12)" ::: "memory");
    else if (kt == 14) asm volatile("s_waitcnt vmcnt(6)" ::: "memory");
    else               asm volatile("s_waitcnt vmcnt(0)" ::: "memory");
    {  // publish A(kt) -> LDSA[kt&1] (swizzled)
      f32x4 a0 = rA[kt%3][0], a1 = rA[kt%3][1], a2 = rA[kt%3][2], a3 = rA[kt%3][3];
      uint4v w0 = { cvt_pk_bf16(a0[0],a0[1]), cvt_pk_bf16(a0[2],a0[3]),
                    cvt_pk_bf16(a1[0],a1[1]), cvt_pk_bf16(a1[2],a1[3]) };
      uint4v w1 = { cvt_pk_bf16(a2[0],a2[1]), cvt_pk_bf16(a2[2],a2[3]),
                    cvt_pk_bf16(a3[0],a3[1]), cvt_pk_bf16(a3[2],a3[3]) };
      *(uint4v*)(sAb + (kt&1)*8192 + awr0) = w0;
      *(uint4v*)(sAb + (kt&1)*8192 + awr1) = w1;
    }
    asm volatile("s_waitcnt lgkmcnt(0)" ::: "memory");
    __builtin_amdgcn_s_barrier();
    if (kt < 13) {   // issue batch kt+3 (safe: buf (kt+3)&3 != readers' kt&3 this iter)
      gl_lds16(bp0, sBb + ((kt+3)&3)*8192 + cb0*1024);
      gl_lds16(bp1, sBb + ((kt+3)&3)*8192 + cb1*1024);
      rA[(kt+3)%3][0] = *(const f32x4*)aR;
      rA[(kt+3)%3][1] = *(const f32x4*)(aR + 4);
      rA[(kt+3)%3][2] = *(const f32x4*)(aR + 8);
      rA[(kt+3)%3][3] = *(const f32x4*)(aR + 12);
      aR += 32; bp0 += 32; bp1 += 32;
    }
    bf16x8 af[4], bfm[4];
#pragma unroll
    for (int mt = 0; mt < 4; ++mt) {
      int row = wrow + mt*16 + m16;
      af[mt] = *(const bf16x8*)(sAb + (kt&1)*8192 + ((row*64 + qq*16) ^ key));
    }
#pragma unroll
    for (int nt = 0; nt < 4; ++nt) {
      int row = wcol + nt*16 + m16;
      bfm[nt] = *(const bf16x8*)(sBb + (kt&3)*8192 + ((row*64 + qq*16) ^ key));
    }
    __builtin_amdgcn_s_setprio(1);
#pragma unroll
    for (int mt = 0; mt < 4; ++mt)
#pragma unroll
      for (int nt = 0; nt < 4; ++nt)
        acc[mt][nt] = __builtin_amdgcn_mfma_f32_16x16x32_bf16(af[mt], bfm[nt], acc[mt][nt], 0, 0, 0);
    __builtin_amdgcn_s_setprio(0);
  }
  float bvv[4];
#pragma unroll
  for (int nt = 0; nt < 4; ++nt) bvv[nt] = bias[n0 + wcol + nt*16 + m16];
  if (z < 2) {
    u16* out = (z == 0) ? Qb : Kb;
#pragma unroll
    for (int mt = 0; mt < 4; ++mt) {
      int gm = m0 + wrow + mt*16 + qq*4;   // C/D: row = quad*4 + reg
#pragma unroll
      for (int nt = 0; nt < 4; ++nt) {
        int gn = n0 + wcol + nt*16 + m16;  // C/D: col = lane&15
#pragma unroll
        for (int r = 0; r < 4; ++r)
          out[(size_t)(gm + r) * E_ + gn] = f2bf(acc[mt][nt][r] + bvv[nt]);
      }
    }
  } else {
    // V: write transposed Vt[(b*E + dim)*S + s]
#pragma unroll
    for (int mt = 0; mt < 4; ++mt) {
      int tok0 = m0 + wrow + mt*16 + qq*4;
      int bb = tok0 >> 10, s0 = tok0 & 1023;
#pragma unroll
      for (int nt = 0; nt < 4; ++nt) {
        int dim = n0 + wcol + nt*16 + m16;
        uint2 wv = { cvt_pk_bf16(acc[mt][nt][0] + bvv[nt], acc[mt][nt][1] + bvv[nt]),
                     cvt_pk_bf16(acc[mt][nt][2] + bvv[nt], acc[mt][nt][3] + bvv[nt]) };
        *(uint2*)(Vt + ((size_t)(bb*E_ + dim))*S_ + s0) = wv;
      }
    }
  }
}

// ---------------- bf16 MFMA GEMM, 128x64 tile, 4-deep counted-vmcnt pipeline ----------------
__global__ __launch_bounds__(256, 3) void gemm_lds(
    const u16* __restrict__ A, const u16* __restrict__ Bw,
    const float* __restrict__ bias, float* __restrict__ out) {
  __shared__ __align__(16) u16 sAD[4*4096];   // 32KB: 4-deep ring
  __shared__ __align__(16) u16 sBD[4*2048];   // 16KB: 4-deep ring
  const int t = threadIdx.x;
  const int hw = blockIdx.x;
  const int wk = (hw & 7) * 128 + (hw >> 3);   // XCD swizzle (bijective)
  const int m0 = (wk >> 3) * 128, n0 = (wk & 7) * 64;
  const int lane = t & 63, wid = t >> 6;
  const int m16 = lane & 15, qq = lane >> 4;
  const int wrow = (wid >> 1) * 64, wcol = (wid & 1) * 32;
  const int key = (lane & 7) << 4;
  f32x4 acc[4][2] = {};
  const int rl0 = ((lane>>2)&1) ^ ((lane>>4)&1);
  const int brow = 2*(lane>>3) + rl0;
  const int bcol = (((lane&1)^rl0)<<3) + ((((lane>>1)&1) ^ ((lane>>3)&1))<<4);
  const int c0 = 2*wid, c1 = 2*wid + 1;
  const u16* a0 = A  + (size_t)(m0 + c0*16 + brow) * E_ + bcol;
  const u16* a1 = A  + (size_t)(m0 + c1*16 + brow) * E_ + bcol;
  const u16* b0 = Bw + (size_t)(n0 + wid*16 + brow) * E_ + bcol;
  char* sAb = (char*)sAD;
  char* sBb = (char*)sBD;
  // prologue: issue batches 0,1,2 (3 ops each)
#pragma unroll
  for (int p = 0; p < 3; ++p) {
    gl_lds16(a0, sAb + p*8192 + c0*1024);
    gl_lds16(a1, sAb + p*8192 + c1*1024);
    gl_lds16(b0, sBb + p*4096 + wid*1024);
    a0 += 32; a1 += 32; b0 += 32;
  }
#pragma unroll
  for (int kt = 0; kt < 16; ++kt) {
    if (kt < 14)       asm volatile("s_waitcnt vmcnt(6)" ::: "memory");
    else if (kt == 14) asm volatile("s_waitcnt vmcnt(3)" ::: "memory");
    else               asm volatile("s_waitcnt vmcnt(0)" ::: "memory");
    __builtin_amdgcn_s_barrier();
    if (kt < 13) {
      gl_lds16(a0, sAb + ((kt+3)&3)*8192 + c0*1024);
      gl_lds16(a1, sAb + ((kt+3)&3)*8192 + c1*1024);
      gl_lds16(b0, sBb + ((kt+3)&3)*4096 + wid*1024);
      a0 += 32; a1 += 32; b0 += 32;
    }
    bf16x8 af[4], bfm[2];
#pragma unroll
    for (int mt = 0; mt < 4; ++mt) {
      int row = wrow + mt*16 + m16;
      af[mt] = *(const bf16x8*)(sAb + (kt&3)*8192 + ((row*64 + qq*16) ^ key));
    }
#pragma unroll
    for (int nt = 0; nt < 2; ++nt) {
      int row = wcol + nt*16 + m16;
      bfm[nt] = *(const bf16x8*)(sBb + (kt&3)*4096 + ((row*64 + qq*16) ^ key));
    }
    __builtin_amdgcn_s_setprio(1);
#pragma unroll
    for (int mt = 0; mt < 4; ++mt)
#pragma unroll
      for (int nt = 0; nt < 2; ++nt)
        acc[mt][nt] = __builtin_amdgcn_mfma_f32_16x16x32_bf16(af[mt], bfm[nt], acc[mt][nt], 0, 0, 0);
    __builtin_amdgcn_s_setprio(0);
  }
  float bv[2];
#pragma unroll
  for (int nt = 0; nt < 2; ++nt) bv[nt] = bias[n0 + wcol + nt*16 + m16];
#pragma unroll
  for (int mt = 0; mt < 4; ++mt) {
    int gm = m0 + wrow + mt*16 + qq*4;
#pragma unroll
    for (int nt = 0; nt < 2; ++nt) {
      int gn = n0 + wcol + nt*16 + m16;
#pragma unroll
      for (int r = 0; r < 4; ++r)
        out[(size_t)(gm + r) * E_ + gn] = acc[mt][nt][r] + bv[nt];
    }
  }
}

// ---------------- MFMA flash attention v2: 32x32 MFMA, in-register P (unchanged R5) --------
#define KST 72   // padded LDS row stride (u16): 144B rows -> 2-way bank aliasing (free)
__global__ __launch_bounds__(256) void attn_mfma(
    const u16* __restrict__ Qb, const u16* __restrict__ Kb, const u16* __restrict__ Vt,
    const int* __restrict__ mask, u16* __restrict__ ctxb) {
  __shared__ __align__(16) u16 sKV[2*64*KST];   // sK | sV^T ; epilogue: O staging (128x72)
  __shared__ __align__(16) float sMask[64];
  __shared__ __align__(16) float sL[128];
  u16* sK = sKV;
  u16* sV = sKV + 64*KST;
  const int t = threadIdx.x;
  const int lane = t & 63, w = t >> 6;
  const int l31 = lane & 31, lh = lane >> 5;
  const int hw = blockIdx.x;
  const int wk = (hw & 7) * 128 + (hw >> 3);
  const int bh = wk >> 3, b = bh >> 3, h = bh & 7;
  const int qblk = (wk & 7) * 128;
  const int q0 = qblk + w * 32;
  bf16x8 qfr[4];
  {
    const u16* qp = Qb + (size_t)(b*S_ + q0 + l31) * E_ + h*D_ + lh*8;
#pragma unroll
    for (int s = 0; s < 4; ++s) qfr[s] = *(const bf16x8*)(qp + s*16);
  }
  f32x16 oacc[2] = {};
  float lpart = 0.f;
  const int srow = t >> 2, sc0 = (t & 3) * 16;
  const u16* kp = Kb + (size_t)(b*S_ + srow) * E_ + h*D_ + sc0;
  const u16* vp = Vt + ((size_t)(b*H_ + h) * D_ + srow) * S_ + sc0;
  uint4 rk0 = *(const uint4*)kp, rk1 = *(const uint4*)(kp + 8);
  uint4 rv0 = *(const uint4*)vp, rv1 = *(const uint4*)(vp + 8);
  float rmsk = 0.f;
  if (t < 64) rmsk = (mask[b*S_ + t] == 0) ? -1e9f : 0.f;
  const float CS = 0.015625f * 1.44269504f;   // (1/64)*log2(e)
  for (int kt = 0; kt < S_; kt += 64) {
    *(uint4*)&sK[srow*KST + sc0]     = rk0;
    *(uint4*)&sK[srow*KST + sc0 + 8] = rk1;
    *(uint4*)&sV[srow*KST + sc0]     = rv0;
    *(uint4*)&sV[srow*KST + sc0 + 8] = rv1;
    if (t < 64) sMask[t] = rmsk;
    __syncthreads();
    if (kt + 64 < S_) {
      kp += (size_t)64 * E_; vp += 64;
      rk0 = *(const uint4*)kp; rk1 = *(const uint4*)(kp + 8);
      rv0 = *(const uint4*)vp; rv1 = *(const uint4*)(vp + 8);
      if (t < 64) rmsk = (mask[b*S_ + kt + 64 + t] == 0) ? -1e9f : 0.f;
    }
    f32x16 sacc[2] = {};
#pragma unroll
    for (int mt = 0; mt < 2; ++mt)
#pragma unroll
      for (int s = 0; s < 4; ++s) {
        bf16x8 kf = *(const bf16x8*)&sK[(mt*32 + l31)*KST + s*16 + lh*8];
        sacc[mt] = __builtin_amdgcn_mfma_f32_32x32x16_bf16(kf, qfr[s], sacc[mt], 0, 0, 0);
      }
    unsigned pw[2][4][2];
#pragma unroll
    for (int mt = 0; mt < 2; ++mt)
#pragma unroll
      for (int g = 0; g < 4; ++g) {
        f32x4 msk = *(const f32x4*)&sMask[mt*32 + g*8 + lh*4];
        float p0 = exp2f(fmaf(sacc[mt][4*g+0], CS, msk[0]));
        float p1 = exp2f(fmaf(sacc[mt][4*g+1], CS, msk[1]));
        float p2 = exp2f(fmaf(sacc[mt][4*g+2], CS, msk[2]));
        float p3 = exp2f(fmaf(sacc[mt][4*g+3], CS, msk[3]));
        lpart += (p0 + p1) + (p2 + p3);
        pw[mt][g][0] = cvt_pk_bf16(p0, p1);
        pw[mt][g][1] = cvt_pk_bf16(p2, p3);
      }
#pragma unroll
    for (int s = 0; s < 4; ++s) {
      const int mt = s >> 1, c = s & 1;
      int2v P1 = plswap(pw[mt][2*c][0], pw[mt][2*c+1][0]);
      int2v P2 = plswap(pw[mt][2*c][1], pw[mt][2*c+1][1]);
      union { uint4v u; bf16x8 h8; } pa;
      pa.u = (uint4v){ (unsigned)P1[0], (unsigned)P2[0], (unsigned)P1[1], (unsigned)P2[1] };
#pragma unroll
      for (int nt = 0; nt < 2; ++nt) {
        bf16x8 vf = *(const bf16x8*)&sV[(nt*32 + l31)*KST + s*16 + lh*8];
        oacc[nt] = __builtin_amdgcn_mfma_f32_32x32x16_bf16(pa.h8, vf, oacc[nt], 0, 0, 0);
      }
    }
    __syncthreads();
  }
  lpart += __shfl_xor(lpart, 32);
  if (lane < 32) sL[w*32 + l31] = lpart;
  f32x4 linv[4];
#pragma unroll
  for (int g = 0; g < 4; ++g) {
    f32x4 lv = *(const f32x4*)&sL[w*32 + 8*g + 4*lh];
    linv[g] = (f32x4){1.0f/lv[0], 1.0f/lv[1], 1.0f/lv[2], 1.0f/lv[3]};
  }
#pragma unroll
  for (int nt = 0; nt < 2; ++nt)
#pragma unroll
    for (int g = 0; g < 4; ++g)
#pragma unroll
      for (int r2 = 0; r2 < 4; ++r2) {
        int qoff = 8*g + 4*lh + r2;
        sKV[(w*32 + qoff)*KST + nt*32 + l31] = f2bf(oacc[nt][4*g+r2] * linv[g][r2]);
      }
  __syncthreads();
  const int row = t >> 1, c0 = (t & 1) * 32;
  uint4 o0 = *(uint4*)&sKV[row*KST + c0];
  uint4 o1 = *(uint4*)&sKV[row*KST + c0 + 8];
  uint4 o2 = *(uint4*)&sKV[row*KST + c0 + 16];
  uint4 o3 = *(uint4*)&sKV[row*KST + c0 + 24];
  u16* dst = ctxb + (size_t)(b*S_ + qblk + row) * E_ + h*D_ + c0;
  *(uint4*)dst = o0;
  *(uint4*)(dst + 8)  = o1;
  *(uint4*)(dst + 16) = o2;
  *(uint4*)(dst + 24) = o3;
}

// ---------------- launch ----------------
extern "C" void kernel_launch(void* const* d_in, const int* in_sizes, int n_in,
                              void* d_out, int out_size, void* d_ws, size_t ws_size,
                              hipStream_t stream) {
  const float* q     = (const float*)d_in[0];
  const float* k     = (const float*)d_in[1];
  const float* v     = (const float*)d_in[2];
  const float* Wq    = (const float*)d_in[3];
  const float* bq    = (const float*)d_in[4];
  const float* Wk    = (const float*)d_in[5];
  const float* bk    = (const float*)d_in[6];
  const float* Wv_sh = (const float*)d_in[7];
  const float* Wv_sp = (const float*)d_in[8];
  const float* bv_sh = (const float*)d_in[9];
  const float* bv_sp = (const float*)d_in[10];
  const float* Wo_sh = (const float*)d_in[11];
  const float* Wo_sp = (const float*)d_in[12];
  const float* bo_sh = (const float*)d_in[13];
  const float* bo_sp = (const float*)d_in[14];
  const int*   mask  = (const int*)d_in[15];
  const int*   lang  = (const int*)d_in[16];

  char* ws = (char*)d_ws;
  size_t off = 0;
  auto alloc = [&](size_t bytes) -> char* {
    char* p = ws + off;
    off += (bytes + 255) & ~(size_t)255;
    return p;
  };
  u16* Qb   = (u16*)alloc((size_t)M_ * E_ * 2);
  u16* Kb   = (u16*)alloc((size_t)M_ * E_ * 2);
  u16* Vt   = (u16*)alloc((size_t)M_ * E_ * 2);
  u16* ctxb = (u16*)alloc((size_t)M_ * E_ * 2);
  u16* Wq_b = (u16*)alloc((size_t)E_ * E_ * 2);
  u16* Wk_b = (u16*)alloc((size_t)E_ * E_ * 2);
  u16* Wv_b = (u16*)alloc((size_t)E_ * E_ * 2);
  u16* Wo_b = (u16*)alloc((size_t)E_ * E_ * 2);
  float* bv_f = (float*)alloc(E_ * 4);
  float* bo_f = (float*)alloc(E_ * 4);

  prep_w<<<E_*E_/1024, 256, 0, stream>>>(Wq, Wk, Wv_sh, Wv_sp, Wo_sh, Wo_sp,
                                         bv_sh, bv_sp, bo_sh, bo_sp, lang,
                                         Wq_b, Wk_b, Wv_b, Wo_b, bv_f, bo_f);

  dim3 qkvgrid(512, 3);
  gemm_qkv<<<qkvgrid, 256, 0, stream>>>(q, k, v, Wq_b, Wk_b, Wv_b,
                                        bq, bk, bv_f, Qb, Kb, Vt);

  attn_mfma<<<1024, 256, 0, stream>>>(Qb, Kb, Vt, mask, ctxb);

  gemm_lds<<<1024, 256, 0, stream>>>(ctxb, Wo_b, bo_f, (float*)d_out);
}